// Round 4
// baseline (705.462 us; speedup 1.0000x reference)
//
#include <hip/hip_runtime.h>
#include <hip/hip_bf16.h>
#include <math.h>

typedef __bf16 bf16x8 __attribute__((ext_vector_type(8)));
typedef float  f32x4  __attribute__((ext_vector_type(4)));
typedef unsigned short ushort_t;

#define MFMA16(a, b, c) __builtin_amdgcn_mfma_f32_16x16x32_bf16((a), (b), (c), 0, 0, 0)

__device__ __forceinline__ float bf2f(ushort_t h) {
    union { unsigned u; float f; } v; v.u = ((unsigned)h) << 16; return v.f;
}
__device__ __forceinline__ ushort_t f2bf(float x) {
    union { float f; unsigned u; } v; v.f = x;
    unsigned r = v.u + 0x7FFFu + ((v.u >> 16) & 1u);
    return (ushort_t)(r >> 16);
}
// async global->LDS, 16B per lane. LDS dest must be wave-uniform base + lane*16.
__device__ __forceinline__ void gl2lds16(const void* g, void* l) {
    __builtin_amdgcn_global_load_lds((__attribute__((address_space(1))) void*)(g),
                                     (__attribute__((address_space(3))) void*)(l),
                                     16, 0, 0);
}

// ---------------------------------------------------------------------------
// Dtype detector: scan first 65536 halfwords of W_qkv for bf16 Inf/NaN/denorm
// bit patterns. fp32 buffer -> low halfwords are uniform mantissa bits ->
// ~256 hits expected. Genuine bf16 N(0,sigma) data -> exactly 0 hits.
// flag = 1 (fp32 inputs) if hits >= 8 else 0 (bf16 inputs).
// ROUND-3 RESULT: flag=1 fired (NaN vanished) => inputs ARE fp32.
// ---------------------------------------------------------------------------
__global__ __launch_bounds__(256) void detect_kernel(const ushort_t* __restrict__ w, int* flag)
{
    __shared__ int cnt[256];
    const int t = threadIdx.x;
    int c = 0;
    for (int i = t; i < 65536; i += 256) {
        const unsigned hw = w[i];
        const unsigned e = (hw >> 7) & 0xFFu;
        if (e == 0xFFu || (e == 0u && (hw & 0x7Fu) != 0u)) c++;
    }
    cnt[t] = c;
    __syncthreads();
    for (int s = 128; s > 0; s >>= 1) {
        if (t < s) cnt[t] += cnt[t + s];
        __syncthreads();
    }
    if (t == 0) flag[0] = (cnt[0] >= 8) ? 1 : 0;
}

// ---------------------------------------------------------------------------
// Canonicalize a float tensor to bf16: fp32 -> RNE-convert, bf16 -> copy.
// ---------------------------------------------------------------------------
__global__ __launch_bounds__(256) void convert_kernel(const void* __restrict__ src,
                                                      ushort_t* __restrict__ dst,
                                                      int n, const int* __restrict__ flag)
{
    const int i0 = (blockIdx.x * 256 + threadIdx.x) * 8;
    if (i0 + 8 > n) return;
    if (flag[0]) {
        const f32x4 a = *(const f32x4*)((const float*)src + i0);
        const f32x4 b = *(const f32x4*)((const float*)src + i0 + 4);
        ushort_t o[8];
        o[0]=f2bf(a[0]); o[1]=f2bf(a[1]); o[2]=f2bf(a[2]); o[3]=f2bf(a[3]);
        o[4]=f2bf(b[0]); o[5]=f2bf(b[1]); o[6]=f2bf(b[2]); o[7]=f2bf(b[3]);
        *(bf16x8*)(dst + i0) = *(const bf16x8*)o;
    } else {
        *(bf16x8*)(dst + i0) = *(const bf16x8*)((const ushort_t*)src + i0);
    }
}

// ---------------------------------------------------------------------------
// qkv GEMM (bf16 out): C[M,N] = A[M,K] * B[N,K]^T + bias[N], fp32 accum.
// 128x128 tile, BK=32, 4 waves, m97-style global_load_lds staging.
// ---------------------------------------------------------------------------
__global__ __launch_bounds__(256) void gemm_bt_bias(
    const ushort_t* __restrict__ A, const ushort_t* __restrict__ B,
    const ushort_t* __restrict__ bias, ushort_t* __restrict__ C,
    int M, int N, int K)
{
    __shared__ __align__(16) ushort_t As[128 * 32];
    __shared__ __align__(16) ushort_t Bs[128 * 32];
    const int tid = threadIdx.x;
    const int w = tid >> 6, l = tid & 63, q = l >> 4, ln = l & 15;
    const int wm = w >> 1, wn = w & 1;
    const int m0 = blockIdx.y * 128, n0 = blockIdx.x * 128;
    const int sr = tid >> 2;
    const int sc = (tid & 3) * 8;

    f32x4 acc[4][4];
    const f32x4 z4 = {0.f, 0.f, 0.f, 0.f};
    for (int i = 0; i < 4; i++) for (int j = 0; j < 4; j++) acc[i][j] = z4;

    for (int k0 = 0; k0 < K; k0 += 32) {
        __syncthreads();
        gl2lds16(A + (size_t)(m0 + sr) * K + k0 + sc,       As + sr * 32 + sc);
        gl2lds16(A + (size_t)(m0 + 64 + sr) * K + k0 + sc,  As + (64 + sr) * 32 + sc);
        gl2lds16(B + (size_t)(n0 + sr) * K + k0 + sc,       Bs + sr * 32 + sc);
        gl2lds16(B + (size_t)(n0 + 64 + sr) * K + k0 + sc,  Bs + (64 + sr) * 32 + sc);
        __syncthreads();
        bf16x8 a[4], bb[4];
        for (int i = 0; i < 4; i++)
            a[i]  = *(const bf16x8*)(As + (wm * 64 + i * 16 + ln) * 32 + q * 8);
        for (int j = 0; j < 4; j++)
            bb[j] = *(const bf16x8*)(Bs + (wn * 64 + j * 16 + ln) * 32 + q * 8);
        for (int i = 0; i < 4; i++)
            for (int j = 0; j < 4; j++)
                acc[i][j] = MFMA16(a[i], bb[j], acc[i][j]);
    }
    for (int j = 0; j < 4; j++) {
        const int n = n0 + wn * 64 + j * 16 + ln;
        const float bv = bf2f(bias[n]);
        for (int i = 0; i < 4; i++) {
            const int mrow = m0 + wm * 64 + i * 16 + q * 4;
            for (int r = 0; r < 4; r++)
                C[(size_t)(mrow + r) * N + n] = f2bf(acc[i][j][r] + bv);
        }
    }
}

// ---------------------------------------------------------------------------
// Final GEMM: same as above but output dtype chosen at runtime by flag:
// flag=1 -> fp32 (reference output dtype for fp32 inputs), flag=0 -> bf16.
// ---------------------------------------------------------------------------
__global__ __launch_bounds__(256) void gemm_bt_bias_out(
    const ushort_t* __restrict__ A, const ushort_t* __restrict__ B,
    const ushort_t* __restrict__ bias, void* __restrict__ C,
    int M, int N, int K, const int* __restrict__ flag)
{
    __shared__ __align__(16) ushort_t As[128 * 32];
    __shared__ __align__(16) ushort_t Bs[128 * 32];
    const int tid = threadIdx.x;
    const int w = tid >> 6, l = tid & 63, q = l >> 4, ln = l & 15;
    const int wm = w >> 1, wn = w & 1;
    const int m0 = blockIdx.y * 128, n0 = blockIdx.x * 128;
    const int sr = tid >> 2;
    const int sc = (tid & 3) * 8;

    f32x4 acc[4][4];
    const f32x4 z4 = {0.f, 0.f, 0.f, 0.f};
    for (int i = 0; i < 4; i++) for (int j = 0; j < 4; j++) acc[i][j] = z4;

    for (int k0 = 0; k0 < K; k0 += 32) {
        __syncthreads();
        gl2lds16(A + (size_t)(m0 + sr) * K + k0 + sc,       As + sr * 32 + sc);
        gl2lds16(A + (size_t)(m0 + 64 + sr) * K + k0 + sc,  As + (64 + sr) * 32 + sc);
        gl2lds16(B + (size_t)(n0 + sr) * K + k0 + sc,       Bs + sr * 32 + sc);
        gl2lds16(B + (size_t)(n0 + 64 + sr) * K + k0 + sc,  Bs + (64 + sr) * 32 + sc);
        __syncthreads();
        bf16x8 a[4], bb[4];
        for (int i = 0; i < 4; i++)
            a[i]  = *(const bf16x8*)(As + (wm * 64 + i * 16 + ln) * 32 + q * 8);
        for (int j = 0; j < 4; j++)
            bb[j] = *(const bf16x8*)(Bs + (wn * 64 + j * 16 + ln) * 32 + q * 8);
        for (int i = 0; i < 4; i++)
            for (int j = 0; j < 4; j++)
                acc[i][j] = MFMA16(a[i], bb[j], acc[i][j]);
    }
    const int f = flag[0];
    for (int j = 0; j < 4; j++) {
        const int n = n0 + wn * 64 + j * 16 + ln;
        const float bv = bf2f(bias[n]);
        for (int i = 0; i < 4; i++) {
            const int mrow = m0 + wm * 64 + i * 16 + q * 4;
            for (int r = 0; r < 4; r++) {
                const float val = acc[i][j][r] + bv;
                const size_t idx = (size_t)(mrow + r) * N + n;
                if (f) ((float*)C)[idx] = val;
                else   ((ushort_t*)C)[idx] = f2bf(val);
            }
        }
    }
}

// ---------------------------------------------------------------------------
// In-place RoPE on Q and K regions of qkv (B*S rows x 6144).
// out[j] = c[j]*x[j] + s[j]*( j<64 ? -x[2j+1] : x[2(j-64)] ),
// angle_i = 10000^(-(2i)/2048)  (EMB_DIM in exponent!)
// ---------------------------------------------------------------------------
__global__ __launch_bounds__(256) void rope_kernel(ushort_t* qkv)
{
    const int bs = blockIdx.x;             // b*2048 + s
    const int s = bs & 2047;
    const int t = threadIdx.x;
    const size_t base = (size_t)bs * 6144;
    float cv[8], sv[8], qa[8], qp[8], ka[8], kp[8];
    for (int u = 0; u < 8; u++) {
        const int e = u * 256 + t;         // h*128 + j
        const int j = e & 127;
        const int p = (j < 64) ? (2 * j + 1) : (2 * (j - 64));
        const int hb = e - j;
        const float ang = powf(10000.0f, -(float)(2 * (j >> 1)) / 2048.0f);
        sincosf((float)s * ang, &sv[u], &cv[u]);
        qa[u] = bf2f(qkv[base + hb + j]);
        qp[u] = bf2f(qkv[base + hb + p]);
        ka[u] = bf2f(qkv[base + 2048 + hb + j]);
        kp[u] = bf2f(qkv[base + 2048 + hb + p]);
    }
    __syncthreads();   // all reads of this row done before any write
    for (int u = 0; u < 8; u++) {
        const int e = u * 256 + t;
        const int j = e & 127;
        const int hb = e - j;
        const float sg = (j < 64) ? -1.0f : 1.0f;
        qkv[base + hb + j]        = f2bf(cv[u] * qa[u] + sv[u] * sg * qp[u]);
        qkv[base + 2048 + hb + j] = f2bf(cv[u] * ka[u] + sv[u] * sg * kp[u]);
    }
}

// ---------------------------------------------------------------------------
// Vt[b,h,d,s] = qkv[b,s,2,h,d]  (transpose V so PV becomes K-contiguous MFMA)
// ---------------------------------------------------------------------------
__global__ __launch_bounds__(256) void vtrans_kernel(const ushort_t* __restrict__ qkv,
                                                     ushort_t* __restrict__ Vt)
{
    __shared__ ushort_t tile[64][130];
    const int blk = blockIdx.x;
    const int st = blk & 31, h = (blk >> 5) & 15, b = blk >> 9;
    const int t = threadIdx.x;
    for (int i = 0; i < 32; i++) {
        const int e = i * 256 + t;
        const int r = e >> 7, c = e & 127;
        tile[r][c] = qkv[(size_t)(b * 2048 + st * 64 + r) * 6144 + 4096 + h * 128 + c];
    }
    __syncthreads();
    const int d = t >> 1, s0 = (t & 1) * 32;
    const size_t obase = ((size_t)(b * 16 + h) * 128 + d) * 2048 + st * 64 + s0;
    for (int k = 0; k < 32; k++)
        Vt[obase + k] = tile[s0 + k][d];
}

// ---------------------------------------------------------------------------
// Flash attention (audited conservative version): plain global->reg->LDS
// staging, padded unswizzled LDS rows. Block = (qtile 64, h, b); 4 waves;
// wave w owns q rows [w*16, w*16+16), softmax state wave-private.
// ---------------------------------------------------------------------------
__global__ __launch_bounds__(256) void flash_kernel(
    const ushort_t* __restrict__ qkv, const ushort_t* __restrict__ Vt,
    const int* __restrict__ mask, ushort_t* __restrict__ AO)
{
    __shared__ __align__(16) ushort_t Qs[64 * 136];
    __shared__ __align__(16) ushort_t Ks[64 * 136];
    __shared__ __align__(16) ushort_t Vs[128 * 72];
    __shared__ __align__(16) ushort_t Ps[64 * 72];
    const int t = threadIdx.x;
    const int w = t >> 6, l = t & 63, q = l >> 4, ln = l & 15;
    const int qb = blockIdx.x * 64, h = blockIdx.y, b = blockIdx.z;
    const size_t brow = (size_t)b * 2048;
    const float scale = 0.08838834764831845f;   // 1/sqrt(128)

    for (int i = 0; i < 4; i++) {
        const int idx = i * 256 + t;
        const int row = idx >> 4, cb = idx & 15;
        bf16x8 v = *(const bf16x8*)(qkv + (brow + qb + row) * 6144 + h * 128 + cb * 8);
        *(bf16x8*)(Qs + row * 136 + cb * 8) = v;
    }

    float m_old[4] = {-1e30f, -1e30f, -1e30f, -1e30f};
    float lsum[4] = {0.f, 0.f, 0.f, 0.f};
    f32x4 o[8];
    const f32x4 z4 = {0.f, 0.f, 0.f, 0.f};
    for (int i = 0; i < 8; i++) o[i] = z4;

    for (int s0 = 0; s0 < 2048; s0 += 64) {
        __syncthreads();
        for (int i = 0; i < 4; i++) {
            const int idx = i * 256 + t;
            const int row = idx >> 4, cb = idx & 15;
            bf16x8 v = *(const bf16x8*)(qkv + (brow + s0 + row) * 6144 + 2048 + h * 128 + cb * 8);
            *(bf16x8*)(Ks + row * 136 + cb * 8) = v;
        }
        for (int i = 0; i < 4; i++) {
            const int idx = i * 256 + t;
            const int row = idx >> 3, cb = idx & 7;
            bf16x8 v = *(const bf16x8*)(Vt + ((size_t)(b * 16 + h) * 128 + row) * 2048 + s0 + cb * 8);
            *(bf16x8*)(Vs + row * 72 + cb * 8) = v;
        }
        __syncthreads();
        f32x4 sc4[4];
        for (int j = 0; j < 4; j++) sc4[j] = z4;
        bf16x8 af[4];
        for (int kk = 0; kk < 4; kk++)
            af[kk] = *(const bf16x8*)(Qs + (w * 16 + ln) * 136 + kk * 32 + q * 8);
        for (int j = 0; j < 4; j++)
            for (int kk = 0; kk < 4; kk++) {
                bf16x8 bfr = *(const bf16x8*)(Ks + (j * 16 + ln) * 136 + kk * 32 + q * 8);
                sc4[j] = MFMA16(af[kk], bfr, sc4[j]);
            }
        float p[4][4], mrow[4] = {-1e30f, -1e30f, -1e30f, -1e30f};
        for (int j = 0; j < 4; j++) {
            const int mk = mask[brow + s0 + j * 16 + ln];
            for (int r = 0; r < 4; r++) {
                float v = sc4[j][r] * scale;
                if (mk == 0 || !isfinite(v)) v = -1e9f;
                p[j][r] = v;
                mrow[r] = fmaxf(mrow[r], v);
            }
        }
        for (int r = 0; r < 4; r++) {
            for (int off = 8; off >= 1; off >>= 1)
                mrow[r] = fmaxf(mrow[r], __shfl_xor(mrow[r], off, 64));
            const float mnew = fmaxf(m_old[r], mrow[r]);
            const float alpha = __expf(m_old[r] - mnew);
            float rs = 0.f;
            for (int j = 0; j < 4; j++) { p[j][r] = __expf(p[j][r] - mnew); rs += p[j][r]; }
            for (int off = 8; off >= 1; off >>= 1)
                rs += __shfl_xor(rs, off, 64);
            lsum[r] = alpha * lsum[r] + rs;
            m_old[r] = mnew;
            for (int jj = 0; jj < 8; jj++) o[jj][r] *= alpha;
        }
        for (int j = 0; j < 4; j++)
            for (int r = 0; r < 4; r++)
                Ps[(w * 16 + q * 4 + r) * 72 + j * 16 + ln] = f2bf(p[j][r]);
        __syncthreads();
        for (int kk = 0; kk < 2; kk++) {
            bf16x8 pa = *(const bf16x8*)(Ps + (w * 16 + ln) * 72 + kk * 32 + q * 8);
            for (int jj = 0; jj < 8; jj++) {
                bf16x8 vb8 = *(const bf16x8*)(Vs + (jj * 16 + ln) * 72 + kk * 32 + q * 8);
                o[jj] = MFMA16(pa, vb8, o[jj]);
            }
        }
    }
    for (int r = 0; r < 4; r++) {
        const float inv = (lsum[r] > 0.f) ? 1.0f / lsum[r] : 0.f;
        const int qrow = qb + w * 16 + q * 4 + r;
        for (int jj = 0; jj < 8; jj++)
            AO[(brow + qrow) * 2048 + h * 128 + jj * 16 + ln] = f2bf(o[jj][r] * inv);
    }
}

extern "C" void kernel_launch(void* const* d_in, const int* in_sizes, int n_in,
                              void* d_out, int out_size, void* d_ws, size_t ws_size,
                              hipStream_t stream)
{
    (void)in_sizes; (void)n_in; (void)out_size; (void)ws_size;
    const void* X    = d_in[0];
    const int*  mask = (const int*)d_in[1];
    const void* Wqkv = d_in[2];
    const void* bqkv = d_in[3];
    const void* Wo   = d_in[4];
    const void* bo   = d_in[5];

    // workspace layout (ushort offsets, all 16B-aligned); ~101 MB total
    int*      flag  = (int*)d_ws;
    ushort_t* Xc    = (ushort_t*)d_ws + 16;            //  8388608 (2*2048*2048)
    ushort_t* Wqkvc = Xc + 8388608;                    // 12582912 (6144*2048)
    ushort_t* bqkvc = Wqkvc + 12582912;                //     6144
    ushort_t* Woc   = bqkvc + 6144;                    //  4194304 (2048*2048)
    ushort_t* boc   = Woc + 4194304;                   //     2048
    ushort_t* qkv   = boc + 2048;                      // 25165824 (4096*6144)
    ushort_t* Vt    = Wqkvc;   // reuse: Wqkv dead after gemm1
    ushort_t* AO    = Xc;      // reuse: X dead after gemm1

    // 0) detect input dtype (fp32 vs bf16) from W_qkv bit patterns
    detect_kernel<<<1, 256, 0, stream>>>((const ushort_t*)Wqkv, flag);
    // 0b) canonicalize all float tensors to bf16
    convert_kernel<<<4096, 256, 0, stream>>>(X,    Xc,    8388608,  flag);
    convert_kernel<<<6144, 256, 0, stream>>>(Wqkv, Wqkvc, 12582912, flag);
    convert_kernel<<<3,    256, 0, stream>>>(bqkv, bqkvc, 6144,     flag);
    convert_kernel<<<2048, 256, 0, stream>>>(Wo,   Woc,   4194304,  flag);
    convert_kernel<<<1,    256, 0, stream>>>(bo,   boc,   2048,     flag);

    // 1) qkv = X @ Wqkv^T + bqkv
    gemm_bt_bias<<<dim3(6144 / 128, 4096 / 128), 256, 0, stream>>>(Xc, Wqkvc, bqkvc, qkv, 4096, 6144, 2048);
    // 2) RoPE in place on Q,K
    rope_kernel<<<4096, 256, 0, stream>>>(qkv);
    // 3) V -> Vt (B,H,D,S)
    vtrans_kernel<<<1024, 256, 0, stream>>>(qkv, Vt);
    // 4) attention
    flash_kernel<<<dim3(32, 16, 2), 256, 0, stream>>>(qkv, Vt, mask, AO);
    // 5) out = AO @ Wo^T + bo  (output dtype follows detected input dtype)
    gemm_bt_bias_out<<<dim3(2048 / 128, 4096 / 128), 256, 0, stream>>>(AO, Woc, boc, d_out, 4096, 2048, 2048, flag);
}

// Round 6
// 657.044 us; speedup vs baseline: 1.0737x; 1.0737x over previous
//
#include <hip/hip_runtime.h>
#include <hip/hip_bf16.h>
#include <math.h>

typedef __bf16 bf16x8 __attribute__((ext_vector_type(8)));
typedef float  f32x4  __attribute__((ext_vector_type(4)));
typedef float  f32x16 __attribute__((ext_vector_type(16)));
typedef unsigned short ushort_t;
typedef ushort_t us4 __attribute__((ext_vector_type(4)));

#define MFMA16(a, b, c) __builtin_amdgcn_mfma_f32_16x16x32_bf16((a), (b), (c), 0, 0, 0)
#define MFMA32(a, b, c) __builtin_amdgcn_mfma_f32_32x32x16_bf16((a), (b), (c), 0, 0, 0)

__device__ __forceinline__ float bf2f(ushort_t h) {
    union { unsigned u; float f; } v; v.u = ((unsigned)h) << 16; return v.f;
}
__device__ __forceinline__ ushort_t f2bf(float x) {
    union { float f; unsigned u; } v; v.f = x;
    unsigned r = v.u + 0x7FFFu + ((v.u >> 16) & 1u);
    return (ushort_t)(r >> 16);
}
// async global->LDS, 16B per lane. LDS dest must be wave-uniform base + lane*16.
__device__ __forceinline__ void gl2lds16(const void* g, void* l) {
    __builtin_amdgcn_global_load_lds((__attribute__((address_space(1))) void*)(g),
                                     (__attribute__((address_space(3))) void*)(l),
                                     16, 0, 0);
}

// ---------------------------------------------------------------------------
// Dtype detector (round-3 verified: flag=1 fires, inputs are fp32).
// ---------------------------------------------------------------------------
__global__ __launch_bounds__(256) void detect_kernel(const ushort_t* __restrict__ w, int* flag)
{
    __shared__ int cnt[256];
    const int t = threadIdx.x;
    int c = 0;
    for (int i = t; i < 65536; i += 256) {
        const unsigned hw = w[i];
        const unsigned e = (hw >> 7) & 0xFFu;
        if (e == 0xFFu || (e == 0u && (hw & 0x7Fu) != 0u)) c++;
    }
    cnt[t] = c;
    __syncthreads();
    for (int s = 128; s > 0; s >>= 1) {
        if (t < s) cnt[t] += cnt[t + s];
        __syncthreads();
    }
    if (t == 0) flag[0] = (cnt[0] >= 8) ? 1 : 0;
}

__global__ __launch_bounds__(256) void convert_kernel(const void* __restrict__ src,
                                                      ushort_t* __restrict__ dst,
                                                      int n, const int* __restrict__ flag)
{
    const int i0 = (blockIdx.x * 256 + threadIdx.x) * 8;
    if (i0 + 8 > n) return;
    if (flag[0]) {
        const f32x4 a = *(const f32x4*)((const float*)src + i0);
        const f32x4 b = *(const f32x4*)((const float*)src + i0 + 4);
        ushort_t o[8];
        o[0]=f2bf(a[0]); o[1]=f2bf(a[1]); o[2]=f2bf(a[2]); o[3]=f2bf(a[3]);
        o[4]=f2bf(b[0]); o[5]=f2bf(b[1]); o[6]=f2bf(b[2]); o[7]=f2bf(b[3]);
        *(bf16x8*)(dst + i0) = *(const bf16x8*)o;
    } else {
        *(bf16x8*)(dst + i0) = *(const bf16x8*)((const ushort_t*)src + i0);
    }
}

// ---------------------------------------------------------------------------
// qkv GEMM (bf16 out): m97-verified pattern, unchanged.
// ---------------------------------------------------------------------------
__global__ __launch_bounds__(256) void gemm_bt_bias(
    const ushort_t* __restrict__ A, const ushort_t* __restrict__ B,
    const ushort_t* __restrict__ bias, ushort_t* __restrict__ C,
    int M, int N, int K)
{
    __shared__ __align__(16) ushort_t As[128 * 32];
    __shared__ __align__(16) ushort_t Bs[128 * 32];
    const int tid = threadIdx.x;
    const int w = tid >> 6, l = tid & 63, q = l >> 4, ln = l & 15;
    const int wm = w >> 1, wn = w & 1;
    const int m0 = blockIdx.y * 128, n0 = blockIdx.x * 128;
    const int sr = tid >> 2;
    const int sc = (tid & 3) * 8;

    f32x4 acc[4][4];
    const f32x4 z4 = {0.f, 0.f, 0.f, 0.f};
    for (int i = 0; i < 4; i++) for (int j = 0; j < 4; j++) acc[i][j] = z4;

    for (int k0 = 0; k0 < K; k0 += 32) {
        __syncthreads();
        gl2lds16(A + (size_t)(m0 + sr) * K + k0 + sc,       As + sr * 32 + sc);
        gl2lds16(A + (size_t)(m0 + 64 + sr) * K + k0 + sc,  As + (64 + sr) * 32 + sc);
        gl2lds16(B + (size_t)(n0 + sr) * K + k0 + sc,       Bs + sr * 32 + sc);
        gl2lds16(B + (size_t)(n0 + 64 + sr) * K + k0 + sc,  Bs + (64 + sr) * 32 + sc);
        __syncthreads();
        bf16x8 a[4], bb[4];
        for (int i = 0; i < 4; i++)
            a[i]  = *(const bf16x8*)(As + (wm * 64 + i * 16 + ln) * 32 + q * 8);
        for (int j = 0; j < 4; j++)
            bb[j] = *(const bf16x8*)(Bs + (wn * 64 + j * 16 + ln) * 32 + q * 8);
        for (int i = 0; i < 4; i++)
            for (int j = 0; j < 4; j++)
                acc[i][j] = MFMA16(a[i], bb[j], acc[i][j]);
    }
    for (int j = 0; j < 4; j++) {
        const int n = n0 + wn * 64 + j * 16 + ln;
        const float bv = bf2f(bias[n]);
        for (int i = 0; i < 4; i++) {
            const int mrow = m0 + wm * 64 + i * 16 + q * 4;
            for (int r = 0; r < 4; r++)
                C[(size_t)(mrow + r) * N + n] = f2bf(acc[i][j][r] + bv);
        }
    }
}

// ---------------------------------------------------------------------------
// Final GEMM: fp32 output when flag=1 (verified), bf16 otherwise.
// ---------------------------------------------------------------------------
__global__ __launch_bounds__(256) void gemm_bt_bias_out(
    const ushort_t* __restrict__ A, const ushort_t* __restrict__ B,
    const ushort_t* __restrict__ bias, void* __restrict__ C,
    int M, int N, int K, const int* __restrict__ flag)
{
    __shared__ __align__(16) ushort_t As[128 * 32];
    __shared__ __align__(16) ushort_t Bs[128 * 32];
    const int tid = threadIdx.x;
    const int w = tid >> 6, l = tid & 63, q = l >> 4, ln = l & 15;
    const int wm = w >> 1, wn = w & 1;
    const int m0 = blockIdx.y * 128, n0 = blockIdx.x * 128;
    const int sr = tid >> 2;
    const int sc = (tid & 3) * 8;

    f32x4 acc[4][4];
    const f32x4 z4 = {0.f, 0.f, 0.f, 0.f};
    for (int i = 0; i < 4; i++) for (int j = 0; j < 4; j++) acc[i][j] = z4;

    for (int k0 = 0; k0 < K; k0 += 32) {
        __syncthreads();
        gl2lds16(A + (size_t)(m0 + sr) * K + k0 + sc,       As + sr * 32 + sc);
        gl2lds16(A + (size_t)(m0 + 64 + sr) * K + k0 + sc,  As + (64 + sr) * 32 + sc);
        gl2lds16(B + (size_t)(n0 + sr) * K + k0 + sc,       Bs + sr * 32 + sc);
        gl2lds16(B + (size_t)(n0 + 64 + sr) * K + k0 + sc,  Bs + (64 + sr) * 32 + sc);
        __syncthreads();
        bf16x8 a[4], bb[4];
        for (int i = 0; i < 4; i++)
            a[i]  = *(const bf16x8*)(As + (wm * 64 + i * 16 + ln) * 32 + q * 8);
        for (int j = 0; j < 4; j++)
            bb[j] = *(const bf16x8*)(Bs + (wn * 64 + j * 16 + ln) * 32 + q * 8);
        for (int i = 0; i < 4; i++)
            for (int j = 0; j < 4; j++)
                acc[i][j] = MFMA16(a[i], bb[j], acc[i][j]);
    }
    const int f = flag[0];
    for (int j = 0; j < 4; j++) {
        const int n = n0 + wn * 64 + j * 16 + ln;
        const float bv = bf2f(bias[n]);
        for (int i = 0; i < 4; i++) {
            const int mrow = m0 + wm * 64 + i * 16 + q * 4;
            for (int r = 0; r < 4; r++) {
                const float val = acc[i][j][r] + bv;
                const size_t idx = (size_t)(mrow + r) * N + n;
                if (f) ((float*)C)[idx] = val;
                else   ((ushort_t*)C)[idx] = f2bf(val);
            }
        }
    }
}

// ---------------------------------------------------------------------------
// RoPE (unchanged, verified).
// ---------------------------------------------------------------------------
__global__ __launch_bounds__(256) void rope_kernel(ushort_t* qkv)
{
    const int bs = blockIdx.x;
    const int s = bs & 2047;
    const int t = threadIdx.x;
    const size_t base = (size_t)bs * 6144;
    float cv[8], sv[8], qa[8], qp[8], ka[8], kp[8];
    for (int u = 0; u < 8; u++) {
        const int e = u * 256 + t;
        const int j = e & 127;
        const int p = (j < 64) ? (2 * j + 1) : (2 * (j - 64));
        const int hb = e - j;
        const float ang = powf(10000.0f, -(float)(2 * (j >> 1)) / 2048.0f);
        sincosf((float)s * ang, &sv[u], &cv[u]);
        qa[u] = bf2f(qkv[base + hb + j]);
        qp[u] = bf2f(qkv[base + hb + p]);
        ka[u] = bf2f(qkv[base + 2048 + hb + j]);
        kp[u] = bf2f(qkv[base + 2048 + hb + p]);
    }
    __syncthreads();
    for (int u = 0; u < 8; u++) {
        const int e = u * 256 + t;
        const int j = e & 127;
        const int hb = e - j;
        const float sg = (j < 64) ? -1.0f : 1.0f;
        qkv[base + hb + j]        = f2bf(cv[u] * qa[u] + sv[u] * sg * qp[u]);
        qkv[base + 2048 + hb + j] = f2bf(cv[u] * ka[u] + sv[u] * sg * kp[u]);
    }
}

// ---------------------------------------------------------------------------
// Vt[b,h,d,s] = qkv[b,s,2,h,d] (unchanged, verified).
// ---------------------------------------------------------------------------
__global__ __launch_bounds__(256) void vtrans_kernel(const ushort_t* __restrict__ qkv,
                                                     ushort_t* __restrict__ Vt)
{
    __shared__ ushort_t tile[64][130];
    const int blk = blockIdx.x;
    const int st = blk & 31, h = (blk >> 5) & 15, b = blk >> 9;
    const int t = threadIdx.x;
    for (int i = 0; i < 32; i++) {
        const int e = i * 256 + t;
        const int r = e >> 7, c = e & 127;
        tile[r][c] = qkv[(size_t)(b * 2048 + st * 64 + r) * 6144 + 4096 + h * 128 + c];
    }
    __syncthreads();
    const int d = t >> 1, s0 = (t & 1) * 32;
    const size_t obase = ((size_t)(b * 16 + h) * 128 + d) * 2048 + st * 64 + s0;
    for (int k = 0; k < 32; k++)
        Vt[obase + k] = tile[s0 + k][d];
}

// ---------------------------------------------------------------------------
// Flash attention v2 — S^T formulation with 32x32x16 MFMA.
//   Block = 128 q-rows (4 waves x 32), grid (16 qtiles, 16 h, 2 b) = 512.
//   S^T = K @ Q^T : A = K (LDS), B = Q (registers, loaded once).
//   C-layout of S^T: col(lane&31) = q-row -> per-lane scalar softmax state,
//   1 shuffle (xor 32) per reduction. P^T stored to per-wave-private Ps as
//   Ps[q][s] (b64-vectorized writes), read back as PV B-frags (b128).
//   O^T = V^T @ P^T : A = V^T (LDS, from Vt), P-frags reused x4 over d-tiles.
//   ROUND-5 FIX: K staging was 2 iters x >>3 (covered 64x64 of the 64x128
//   tile -> cols 64..127 uninitialized -> NaN). Now 4 iters, row=c>>4, cb=c&15.
// ---------------------------------------------------------------------------
__global__ __launch_bounds__(256) void flash_kernel(
    const ushort_t* __restrict__ qkv, const ushort_t* __restrict__ Vt,
    const int* __restrict__ mask, ushort_t* __restrict__ AO)
{
    __shared__ __align__(16) ushort_t Ks[64 * 136];
    __shared__ __align__(16) ushort_t Vs[128 * 136];
    __shared__ __align__(16) ushort_t Ps[4 * 32 * 72];
    const int t = threadIdx.x;
    const int w = t >> 6, l = t & 63, lq = l & 31, q2 = l >> 5;
    const int qb = blockIdx.x * 128, h = blockIdx.y, b = blockIdx.z;
    const size_t brow = (size_t)b * 2048;
    const float scale = 0.08838834764831845f;   // 1/sqrt(128)
    const int qrow = qb + w * 32 + lq;          // this lane's q-row (pair l,l+32 share it)

    // Q as register-resident B-frags: b[n=lane&31=q-row][k=d : q2*8+j]
    bf16x8 qf[8];
#pragma unroll
    for (int kb = 0; kb < 8; kb++)
        qf[kb] = *(const bf16x8*)(qkv + (brow + qrow) * 6144 + h * 128 + kb * 16 + q2 * 8);

    float m_old = -1e30f, lsum = 0.f;
    f32x16 acc_o[4];
#pragma unroll
    for (int dt = 0; dt < 4; dt++)
#pragma unroll
        for (int r = 0; r < 16; r++) acc_o[dt][r] = 0.f;

    for (int s0 = 0; s0 < 2048; s0 += 64) {
        const int mk = mask[brow + s0 + l];
        const unsigned long long bm = __ballot(mk != 0);
        __syncthreads();   // prev-iter LDS frag reads done
        // stage K tile (64 s x 128 d) -> Ks pitch 136: 1024 chunks of 8 bf16
#pragma unroll
        for (int i = 0; i < 4; i++) {
            const int c = i * 256 + t;
            const int row = c >> 4, cb = c & 15;
            *(bf16x8*)(Ks + row * 136 + cb * 8) =
                *(const bf16x8*)(qkv + (brow + s0 + row) * 6144 + 2048 + h * 128 + cb * 8);
        }
        // stage V^T tile (128 d x 64 s) from Vt -> Vs pitch 136: 1024 chunks
#pragma unroll
        for (int i = 0; i < 4; i++) {
            const int c = i * 256 + t;
            const int row = c >> 3, cb = c & 7;
            *(bf16x8*)(Vs + row * 136 + cb * 8) =
                *(const bf16x8*)(Vt + ((size_t)(b * 16 + h) * 128 + row) * 2048 + s0 + cb * 8);
        }
        __syncthreads();
        // S^T = K @ Q^T : 2 m-tiles (s) x 8 k-blocks (d)
        f32x16 sa[2];
#pragma unroll
        for (int mt = 0; mt < 2; mt++) {
#pragma unroll
            for (int r = 0; r < 16; r++) sa[mt][r] = 0.f;
#pragma unroll
            for (int kb = 0; kb < 8; kb++) {
                bf16x8 a = *(const bf16x8*)(Ks + (mt * 32 + lq) * 136 + kb * 16 + q2 * 8);
                sa[mt] = MFMA32(a, qf[kb], sa[mt]);
            }
        }
        // online softmax: lane owns one q-row; s spread over 32 regs + partner lane
        float p[32];
        float mr = -1e30f;
#pragma unroll
        for (int mt = 0; mt < 2; mt++)
#pragma unroll
            for (int r = 0; r < 16; r++) {
                const int srow = mt * 32 + (r & 3) + 8 * (r >> 2) + 4 * q2;
                const float bias = ((bm >> srow) & 1ull) ? 0.f : -1e9f;
                const float v = sa[mt][r] * scale + bias;
                p[mt * 16 + r] = v;
                mr = fmaxf(mr, v);
            }
        mr = fmaxf(mr, __shfl_xor(mr, 32, 64));
        const float mnew = fmaxf(m_old, mr);
        const float alpha = __expf(m_old - mnew);
        float rs = 0.f;
#pragma unroll
        for (int i = 0; i < 32; i++) { p[i] = __expf(p[i] - mnew); rs += p[i]; }
        rs += __shfl_xor(rs, 32, 64);
        lsum = alpha * lsum + rs;
        m_old = mnew;
#pragma unroll
        for (int dt = 0; dt < 4; dt++)
#pragma unroll
            for (int r = 0; r < 16; r++) acc_o[dt][r] *= alpha;
        // P -> Ps[q][s], wave-private, b64 writes (4 consecutive s per reg-quad)
#pragma unroll
        for (int mt = 0; mt < 2; mt++)
#pragma unroll
            for (int r2 = 0; r2 < 4; r2++) {
                us4 pk;
#pragma unroll
                for (int j = 0; j < 4; j++) pk[j] = f2bf(p[mt * 16 + r2 * 4 + j]);
                *(us4*)(Ps + (w * 32 + lq) * 72 + mt * 32 + r2 * 8 + q2 * 4) = pk;
            }
        // O^T += V^T @ P^T : P B-frags (reused x4), V A-frags
        bf16x8 pf[4];
#pragma unroll
        for (int kb = 0; kb < 4; kb++)
            pf[kb] = *(const bf16x8*)(Ps + (w * 32 + lq) * 72 + kb * 16 + q2 * 8);
#pragma unroll
        for (int dt = 0; dt < 4; dt++)
#pragma unroll
            for (int kb = 0; kb < 4; kb++) {
                bf16x8 va = *(const bf16x8*)(Vs + (dt * 32 + lq) * 136 + kb * 16 + q2 * 8);
                acc_o[dt] = MFMA32(va, pf[kb], acc_o[dt]);
            }
    }
    __syncthreads();   // all PV reads of Vs done before epilogue reuses it
    // epilogue: divide by lsum, transpose O^T -> row-major via Vs (wave-private rows)
    const float inv = (lsum > 0.f) ? 1.0f / lsum : 0.f;
#pragma unroll
    for (int dt = 0; dt < 4; dt++)
#pragma unroll
        for (int r2 = 0; r2 < 4; r2++) {
            us4 ov;
#pragma unroll
            for (int j = 0; j < 4; j++) ov[j] = f2bf(acc_o[dt][r2 * 4 + j] * inv);
            *(us4*)(Vs + (w * 32 + lq) * 136 + dt * 32 + r2 * 8 + q2 * 4) = ov;
        }
#pragma unroll
    for (int i = 0; i < 8; i++) {
        const int row = i * 4 + (l >> 4), ch = l & 15;
        bf16x8 vv = *(const bf16x8*)(Vs + (w * 32 + row) * 136 + ch * 8);
        *(bf16x8*)(AO + (brow + qb + w * 32 + row) * 2048 + h * 128 + ch * 8) = vv;
    }
}

extern "C" void kernel_launch(void* const* d_in, const int* in_sizes, int n_in,
                              void* d_out, int out_size, void* d_ws, size_t ws_size,
                              hipStream_t stream)
{
    (void)in_sizes; (void)n_in; (void)out_size; (void)ws_size;
    const void* X    = d_in[0];
    const int*  mask = (const int*)d_in[1];
    const void* Wqkv = d_in[2];
    const void* bqkv = d_in[3];
    const void* Wo   = d_in[4];
    const void* bo   = d_in[5];

    int*      flag  = (int*)d_ws;
    ushort_t* Xc    = (ushort_t*)d_ws + 16;
    ushort_t* Wqkvc = Xc + 8388608;
    ushort_t* bqkvc = Wqkvc + 12582912;
    ushort_t* Woc   = bqkvc + 6144;
    ushort_t* boc   = Woc + 4194304;
    ushort_t* qkv   = boc + 2048;
    ushort_t* Vt    = Wqkvc;   // reuse: Wqkv dead after gemm1
    ushort_t* AO    = Xc;      // reuse: X dead after gemm1

    detect_kernel<<<1, 256, 0, stream>>>((const ushort_t*)Wqkv, flag);
    convert_kernel<<<4096, 256, 0, stream>>>(X,    Xc,    8388608,  flag);
    convert_kernel<<<6144, 256, 0, stream>>>(Wqkv, Wqkvc, 12582912, flag);
    convert_kernel<<<3,    256, 0, stream>>>(bqkv, bqkvc, 6144,     flag);
    convert_kernel<<<2048, 256, 0, stream>>>(Wo,   Woc,   4194304,  flag);
    convert_kernel<<<1,    256, 0, stream>>>(bo,   boc,   2048,     flag);

    gemm_bt_bias<<<dim3(6144 / 128, 4096 / 128), 256, 0, stream>>>(Xc, Wqkvc, bqkvc, qkv, 4096, 6144, 2048);
    rope_kernel<<<4096, 256, 0, stream>>>(qkv);
    vtrans_kernel<<<1024, 256, 0, stream>>>(qkv, Vt);
    flash_kernel<<<dim3(16, 16, 2), 256, 0, stream>>>(qkv, Vt, mask, AO);
    gemm_bt_bias_out<<<dim3(2048 / 128, 4096 / 128), 256, 0, stream>>>(AO, Woc, boc, d_out, 4096, 2048, 2048, flag);
}